// Round 8
// baseline (156.923 us; speedup 1.0000x reference)
//
#include <hip/hip_runtime.h>
#include <cstddef>
#include <cstdint>

#define L_SEQ 4096
#define EMB   1024
#define NH    16
#define HD    64
#define N3    3072
#define CHUNK 64
#define NCHUNK 64
#define EPS 1e-6f

typedef __attribute__((ext_vector_type(8))) short   bf16x8;
typedef __attribute__((ext_vector_type(4))) short   bf16x4;
typedef __attribute__((ext_vector_type(4))) float   floatx4;

#define AS1 __attribute__((address_space(1)))
#define AS3 __attribute__((address_space(3)))

__device__ __forceinline__ void gload_lds16(const void* g, void* l) {
    __builtin_amdgcn_global_load_lds((AS1 const unsigned int*)g,
                                     (AS3 unsigned int*)l, 16, 0, 0);
}

// round-to-nearest-even fp32 -> bf16 bits
__device__ __forceinline__ short f2bf(float f) {
    union { float f; unsigned u; } a; a.f = f;
    unsigned r = a.u + 0x7fffu + ((a.u >> 16) & 1u);
    return (short)(r >> 16);
}
__device__ __forceinline__ float bf2f(short s) {
    union { unsigned u; float f; } a; a.u = ((unsigned)(unsigned short)s) << 16;
    return a.f;
}

// ---------------------------------------------------------------------------
// K0: fused prep — blocks [0,2048): x->bf16; [2048,2816): qkv_w^T;
// [2816,3072): out_w^T.
// ---------------------------------------------------------------------------
__device__ __forceinline__ void transpose_tile(const float* __restrict__ W,
                                               short* __restrict__ WT,
                                               int K, int N, int bx, int by,
                                               float (*t)[65], int tid)
{
    const int r  = tid >> 4;
    const int c4 = (tid & 15) << 2;
#pragma unroll
    for (int s = 0; s < 4; ++s) {
        const int k = r + s * 16;
        const floatx4 v = *(const floatx4*)&W[(size_t)(by * 64 + k) * N + bx * 64 + c4];
        t[k][c4 + 0] = v[0]; t[k][c4 + 1] = v[1];
        t[k][c4 + 2] = v[2]; t[k][c4 + 3] = v[3];
    }
    __syncthreads();
#pragma unroll
    for (int s = 0; s < 4; ++s) {
        const int n = r + s * 16;
        bf16x4 o;
        o[0] = f2bf(t[c4 + 0][n]); o[1] = f2bf(t[c4 + 1][n]);
        o[2] = f2bf(t[c4 + 2][n]); o[3] = f2bf(t[c4 + 3][n]);
        *(bf16x4*)&WT[(size_t)(bx * 64 + n) * K + by * 64 + c4] = o;
    }
}

__global__ __launch_bounds__(256)
void prep(const float* __restrict__ x, short* __restrict__ xb,
          const float* __restrict__ qkv_w, short* __restrict__ qwt,
          const float* __restrict__ out_w, short* __restrict__ owt)
{
    __shared__ float t[64][65];
    const int b = blockIdx.x;
    const int tid = threadIdx.x;
    if (b < 2048) {
        const int i = b * 256 + tid;
        const floatx4 a = *(const floatx4*)(x + (size_t)i * 8);
        const floatx4 c = *(const floatx4*)(x + (size_t)i * 8 + 4);
        bf16x8 o;
        o[0] = f2bf(a[0]); o[1] = f2bf(a[1]); o[2] = f2bf(a[2]); o[3] = f2bf(a[3]);
        o[4] = f2bf(c[0]); o[5] = f2bf(c[1]); o[6] = f2bf(c[2]); o[7] = f2bf(c[3]);
        *(bf16x8*)(xb + (size_t)i * 8) = o;
    } else if (b < 2048 + 768) {
        const int u = b - 2048;
        transpose_tile(qkv_w, qwt, EMB, N3, u % 48, u / 48, t, tid);
    } else {
        const int u = b - 2816;
        transpose_tile(out_w, owt, EMB, EMB, u & 15, u >> 4, t, tid);
    }
}

// ---------------------------------------------------------------------------
// K1: qkv GEMM — v4: 128x192 tile, 256 threads (4 waves, 1Mx4N, per-wave
// 128x48), LDS 80 KB -> 2 blocks/CU (cross-block overlap fills barrier
// stalls; R6/R7's 112KB variant was 1/CU, MfmaUtil ~31%). Grid 32x16=512.
// Same 8-phase schedule + 3-bit XOR swizzle (verified R6/R7).
// LDS (shorts): buf0.A=0(8192) buf0.B=8192(12288) buf1.A=20480 buf1.B=28672.
// Loads/K-tile: A=4, B=6. vmcnt(6) at prologue/ph4/ph8:
//   steady entering ph1: S=6 (buf1.B(t1) from prev ph7)
//   ph1:+4(buf1.A t1) ph2:+6(buf0.B t0+2) ph4:vmcnt(6) drains S+A ✓
//   ph5:+4(buf0.A t0+2) ph7:+6(buf1.B t1+2) ph8:vmcnt(6) drains buf0(t0+2) ✓
// ---------------------------------------------------------------------------
#define MFMA16 __builtin_amdgcn_mfma_f32_16x16x32_bf16

__global__ __launch_bounds__(256, 2)
void mfma_gemm_qkv256(const short* __restrict__ A, const short* __restrict__ BT,
                      const float* __restrict__ bias,
                      short* __restrict__ OQ, short* __restrict__ OK,
                      short* __restrict__ OV)
{
    __shared__ __align__(16) short lds[40960];   // 80 KiB
    const int tid  = threadIdx.x;
    const int lane = tid & 63;
    const int wave = tid >> 6;           // 0..3
    const int wc   = wave;               // N quarter, 48 cols each
    const int frow = lane & 15;
    const int quad = lane >> 4;
    const int q8   = quad * 8;
    // XCD remap: xcd = fid&7 owns 8bx x 8by (concurrent set A 2MB + B 3MB)
    const int fid = blockIdx.y * 16 + blockIdx.x;      // 0..511
    const int xg  = fid & 7;
    const int j   = fid >> 3;                          // 0..63
    const int bx  = (xg & 1) * 8 + (j & 7);            // 0..15 (192 cols)
    const int by  = (xg >> 1) * 8 + (j >> 3);          // 0..31 (128 rows)

    const short* Ab = A  + (size_t)(by * 128) * 1024;
    const short* Bb = BT + (size_t)(bx * 192) * 1024;

    const int trow = tid >> 3;                       // 0..31
    const int ccol = (tid & 7) * 8;                  // dst col chunk, shorts
    const int scol = ccol ^ ((trow & 14) << 2);      // 3-bit swizzled src col
    const int sx   = (frow & 14) << 2;               // read-side XOR, shorts
    const int wcb  = wc * 48 + frow;                 // B fragment row base

// A stage: 128 rows (4 x 32), rows j*32+trow ((j*32+trow)&14 == trow&14)
#define STG_A(LBASE, GPTR) do {                                             \
        const short* g_ = (GPTR);                                           \
        _Pragma("unroll")                                                   \
        for (int j_ = 0; j_ < 4; ++j_) {                                    \
            const int r_ = j_ * 32 + trow;                                  \
            gload_lds16(g_ + (size_t)r_ * 1024 + scol,                      \
                        &lds[(LBASE) + r_ * 64 + ccol]);                    \
        }                                                                   \
    } while (0)

// B stage: 192 rows (6 x 32)
#define STG_B(LBASE, GPTR) do {                                             \
        const short* g_ = (GPTR);                                           \
        _Pragma("unroll")                                                   \
        for (int j_ = 0; j_ < 6; ++j_) {                                    \
            const int r_ = j_ * 32 + trow;                                  \
            gload_lds16(g_ + (size_t)r_ * 1024 + scol,                      \
                        &lds[(LBASE) + r_ * 64 + ccol]);                    \
        }                                                                   \
    } while (0)

#define LDA(BASE, R, KS) \
    (*(const bf16x8*)&lds[(BASE) + (R) * 64 + ((((KS) * 32) + q8) ^ sx)])

    floatx4 acc[8][3] = {};
    bf16x8  bq[3][2];

#define PHASE(ABASE, BBASE, QD, RDB, VM, ...) do {                          \
        const int Rr_ = (QD) * 32 + frow;                                   \
        bf16x8 a0_ = LDA((ABASE), Rr_,      0);                             \
        bf16x8 a1_ = LDA((ABASE), Rr_,      1);                             \
        bf16x8 a2_ = LDA((ABASE), Rr_ + 16, 0);                             \
        bf16x8 a3_ = LDA((ABASE), Rr_ + 16, 1);                             \
        if (RDB) {                                                          \
            _Pragma("unroll")                                               \
            for (int ni_ = 0; ni_ < 3; ++ni_) {                             \
                bq[ni_][0] = LDA((BBASE), wcb + ni_ * 16, 0);               \
                bq[ni_][1] = LDA((BBASE), wcb + ni_ * 16, 1);               \
            }                                                               \
        }                                                                   \
        __VA_ARGS__;                                                        \
        __builtin_amdgcn_sched_barrier(0);                                  \
        __builtin_amdgcn_s_barrier();                                       \
        asm volatile("s_waitcnt lgkmcnt(0)" ::: "memory");                  \
        __builtin_amdgcn_sched_barrier(0);                                  \
        __builtin_amdgcn_s_setprio(1);                                      \
        _Pragma("unroll")                                                   \
        for (int ni_ = 0; ni_ < 3; ++ni_) {                                 \
            acc[2*(QD)  ][ni_] = MFMA16(a0_, bq[ni_][0], acc[2*(QD)  ][ni_], 0,0,0); \
            acc[2*(QD)  ][ni_] = MFMA16(a1_, bq[ni_][1], acc[2*(QD)  ][ni_], 0,0,0); \
            acc[2*(QD)+1][ni_] = MFMA16(a2_, bq[ni_][0], acc[2*(QD)+1][ni_], 0,0,0); \
            acc[2*(QD)+1][ni_] = MFMA16(a3_, bq[ni_][1], acc[2*(QD)+1][ni_], 0,0,0); \
        }                                                                   \
        __builtin_amdgcn_s_setprio(0);                                      \
        if (VM) asm volatile("s_waitcnt vmcnt(6)" ::: "memory");            \
        __builtin_amdgcn_s_barrier();                                       \
        __builtin_amdgcn_sched_barrier(0);                                  \
    } while (0)

    // prologue: tile0 A+B -> buf0, tile1 B -> buf1 (16 issues), drain to 6
    STG_A(0,     Ab);                    // buf0.A (t0)
    STG_B(8192,  Bb);                    // buf0.B (t0)
    STG_B(28672, Bb + 64);               // buf1.B (t1)
    asm volatile("s_waitcnt vmcnt(6)" ::: "memory");
    __builtin_amdgcn_s_barrier();
    __builtin_amdgcn_sched_barrier(0);

#pragma unroll 1
    for (int it = 0; it < 8; ++it) {
        const int k1  = (2 * it + 1) * 64;             // odd tile k-offset
        const int kn0 = ((2 * it + 2) & 15) * 64;      // next even (wrapped)
        const int kn1 = ((2 * it + 3) & 15) * 64;      // next odd (wrapped)

        // even tile from buf0
        PHASE(0, 8192, 0, 1, 0, STG_A(20480, Ab + k1));
        PHASE(0, 8192, 1, 0, 0, STG_B(8192, Bb + kn0));
        PHASE(0, 8192, 2, 0, 0, ((void)0));
        PHASE(0, 8192, 3, 0, 1, ((void)0));
        // odd tile from buf1
        PHASE(20480, 28672, 0, 1, 0, STG_A(0, Ab + kn0));
        PHASE(20480, 28672, 1, 0, 0, ((void)0));
        PHASE(20480, 28672, 2, 0, 0, STG_B(28672, Bb + kn1));
        PHASE(20480, 28672, 3, 0, 1, ((void)0));
    }

    __syncthreads();   // full drain (incl. wrapped tail stages); LDS reuse safe

    // epilogue: per-wave 128x48 repack -> bias + elu(q,k) -> head-major scatter
    const int wbase = wave * 6144;
    const int colg0 = bx * 192 + wc * 48;
    const int L0 = by * 128;
#pragma unroll
    for (int ni = 0; ni < 3; ++ni) {
        const int n = colg0 + ni * 16 + frow;
        const float bv = bias[n];
        const bool do_elu = (n >> 10) < 2;
#pragma unroll
        for (int mi = 0; mi < 8; ++mi)
#pragma unroll
            for (int r = 0; r < 4; ++r) {
                float v = acc[mi][ni][r] + bv;
                if (do_elu) v = (v > 0.f) ? (v + 1.f) : __expf(v);
                lds[wbase + (mi * 16 + quad * 4 + r) * 48 + ni * 16 + frow] = f2bf(v);
            }
    }
#pragma unroll
    for (int s = 0; s < 12; ++s) {
        const int chunk = s * 64 + lane;     // 768 chunks of 8 shorts
        const int row = chunk / 6, cc = (chunk % 6) * 8;
        const bf16x8 val = *(const bf16x8*)&lds[wbase + row * 48 + cc];
        const int n0 = colg0 + cc;
        const int rsel = n0 >> 10;
        const int h = (n0 & 1023) >> 6;
        const int d = n0 & 63;
        short* base = (rsel == 0) ? OQ : (rsel == 1 ? OK : OV);
        *(bf16x8*)&base[((size_t)(h * L_SEQ + L0 + row)) * HD + d] = val;
    }
#undef PHASE
#undef LDA
#undef STG_A
#undef STG_B
}

// ---------------------------------------------------------------------------
// K5: out-projection GEMM, 64x128 tile (512 blocks = 2/CU). (R7, passed)
// ---------------------------------------------------------------------------
__global__ __launch_bounds__(256)
void mfma_gemm_out(const short* __restrict__ A, const short* __restrict__ BT,
                   const float* __restrict__ bias, float* __restrict__ OF,
                   int N, int K)
{
    __shared__ __align__(16) short smem[12288];
    const int tid  = threadIdx.x;
    const int lane = tid & 63;
    const int wave = tid >> 6;
    const int wm = (wave >> 1) * 32;
    const int wn = (wave & 1) * 64;
    const int fid = blockIdx.y * 8 + blockIdx.x;
    const int nf  = (fid & 7) * 64 + (fid >> 3);
    const int bx  = nf & 7;
    const int by  = nf >> 3;
    const int frow = lane & 15;
    const int quad = lane >> 4;
    const int q8   = quad << 3;
    const int sx   = (frow & 14) << 2;

    const short* Ab = A  + (size_t)(by * 64) * K;
    const short* Bb = BT + (size_t)(bx * 128) * K;

    floatx4 acc[2][4] = {};

    for (int k0 = 0; k0 < K; k0 += 64) {
#pragma unroll
        for (int q = 0; q < 2; ++q) {
            const int idx = q * 256 + tid;
            const int row = idx >> 3;
            const int c8  = (idx & 7) << 3;
            gload_lds16(Ab + (size_t)row * K + k0 + (c8 ^ ((row & 14) << 2)),
                        &smem[idx << 3]);
        }
#pragma unroll
        for (int q = 0; q < 4; ++q) {
            const int idx = q * 256 + tid;
            const int row = idx >> 3;
            const int c8  = (idx & 7) << 3;
            gload_lds16(Bb + (size_t)row * K + k0 + (c8 ^ ((row & 14) << 2)),
                        &smem[4096 + (idx << 3)]);
        }
        __syncthreads();
        bf16x8 af[2][2], bfv[4][2];
#pragma unroll
        for (int mi = 0; mi < 2; ++mi)
#pragma unroll
            for (int ks = 0; ks < 2; ++ks)
                af[mi][ks] = *(const bf16x8*)
                    &smem[(wm + mi * 16 + frow) * 64 + ((ks * 32 + q8) ^ sx)];
#pragma unroll
        for (int ni = 0; ni < 4; ++ni)
#pragma unroll
            for (int ks = 0; ks < 2; ++ks)
                bfv[ni][ks] = *(const bf16x8*)
                    &smem[4096 + (wn + ni * 16 + frow) * 64 + ((ks * 32 + q8) ^ sx)];
#pragma unroll
        for (int mi = 0; mi < 2; ++mi)
#pragma unroll
            for (int ni = 0; ni < 4; ++ni) {
                acc[mi][ni] = MFMA16(af[mi][0], bfv[ni][0], acc[mi][ni], 0, 0, 0);
                acc[mi][ni] = MFMA16(af[mi][1], bfv[ni][1], acc[mi][ni], 0, 0, 0);
            }
        __syncthreads();
    }

    const int rq = quad << 2;
#pragma unroll
    for (int ni = 0; ni < 4; ++ni) {
        const int n = bx * 128 + wn + ni * 16 + frow;
        const float bv = bias[n];
#pragma unroll
        for (int mi = 0; mi < 2; ++mi)
#pragma unroll
            for (int r = 0; r < 4; ++r) {
                const int m = by * 64 + wm + mi * 16 + rq + r;
                OF[(size_t)m * N + n] = acc[mi][ni][r] + bv;
            }
    }
}

// ---------------------------------------------------------------------------
// K2: per-(head,chunk) state sums, MFMA version. (unchanged, passed)
// ---------------------------------------------------------------------------
#define SP 72

__global__ __launch_bounds__(256, 4)
void chunk_state(const short* __restrict__ Kb, const short* __restrict__ Vb,
                 short* __restrict__ ScTb, float* __restrict__ zc)
{
    __shared__ __align__(16) short Vt[64 * SP];   // V^T: rows e, cols l
    __shared__ __align__(16) short Kt[64 * SP];   // K'^T: rows d, cols l
    const int c = blockIdx.x, h = blockIdx.y;
    const int tid = threadIdx.x, lane = tid & 63, wave = tid >> 6;
    const int frow = lane & 15;
    const int quad = lane >> 4;
    const int fko  = quad << 3;
    const int wm   = wave << 4;
    const short* Kg = Kb + ((size_t)h * L_SEQ + (size_t)c * CHUNK) * HD;
    const short* Vg = Vb + ((size_t)h * L_SEQ + (size_t)c * CHUNK) * HD;

#pragma unroll
    for (int q = 0; q < 2; ++q) {
        const int idx = q * 256 + tid;            // 512 chunks of 8
        const int l = idx >> 3, c8 = (idx & 7) << 3;
        const bf16x8 vv = *(const bf16x8*)&Vg[l * 64 + c8];
        const bf16x8 kk = *(const bf16x8*)&Kg[l * 64 + c8];
#pragma unroll
        for (int j = 0; j < 8; ++j) {
            Vt[(c8 + j) * SP + l] = vv[j];
            Kt[(c8 + j) * SP + l] = kk[j];
        }
    }
    __syncthreads();

    const bf16x8 af0 = *(const bf16x8*)&Vt[(wm + frow) * SP + fko];
    const bf16x8 af1 = *(const bf16x8*)&Vt[(wm + frow) * SP + 32 + fko];

    floatx4 acc[4] = {};
#pragma unroll
    for (int n = 0; n < 4; ++n) {
        const bf16x8 kf0 = *(const bf16x8*)&Kt[(n * 16 + frow) * SP + fko];
        const bf16x8 kf1 = *(const bf16x8*)&Kt[(n * 16 + frow) * SP + 32 + fko];
        acc[n] = MFMA16(af0, kf0, acc[n], 0, 0, 0);
        acc[n] = MFMA16(af1, kf1, acc[n], 0, 0, 0);
    }

    short* Sout = ScTb + (size_t)(h * NCHUNK + c) * 4096;
#pragma unroll
    for (int n = 0; n < 4; ++n)
#pragma unroll
        for (int r = 0; r < 4; ++r) {
            const int e = wm + quad * 4 + r;
            const int d = n * 16 + frow;
            Sout[e * 64 + d] = f2bf(acc[n][r]);
        }

    if (wave == 0) {   // z[d] = sum_l K'[l][d] via all-ones A fragment
        bf16x8 ones;
#pragma unroll
        for (int j = 0; j < 8; ++j) ones[j] = (short)0x3F80;
        floatx4 zacc[4] = {};
#pragma unroll
        for (int n = 0; n < 4; ++n) {
            const bf16x8 kf0 = *(const bf16x8*)&Kt[(n * 16 + frow) * SP + fko];
            const bf16x8 kf1 = *(const bf16x8*)&Kt[(n * 16 + frow) * SP + 32 + fko];
            zacc[n] = MFMA16(ones, kf0, zacc[n], 0, 0, 0);
            zacc[n] = MFMA16(ones, kf1, zacc[n], 0, 0, 0);
        }
        if (quad == 0) {
#pragma unroll
            for (int n = 0; n < 4; ++n)
                zc[(size_t)(h * NCHUNK + c) * 64 + n * 16 + frow] = zacc[n][0];
        }
    }
}

// ---------------------------------------------------------------------------
// K3: exclusive prefix over chunks, 16-deep batches. (R7, passed)
// ---------------------------------------------------------------------------
__global__ __launch_bounds__(256)
void prefix_scan(const short* __restrict__ ScTb, const float* __restrict__ zc,
                 short* __restrict__ S0b)
{
    const int g = blockIdx.x * 256 + threadIdx.x;
    const int h  = g >> 12;
    const int ed = g & 4095;
    const int e  = ed >> 6;
    const int d  = ed & 63;
    const short* src = ScTb + (size_t)h * NCHUNK * 4096 + ed;
    float run = 0.f;
    for (int cb = 0; cb < NCHUNK; cb += 16) {
        short v[16];
#pragma unroll
        for (int u = 0; u < 16; ++u) v[u] = src[(size_t)(cb + u) * 4096];
#pragma unroll
        for (int u = 0; u < 16; ++u) {
            S0b[((size_t)((h * NCHUNK + cb + u) * 65 + e)) * 64 + d] = f2bf(run);
            run += bf2f(v[u]);
        }
    }
    if (g < NH * HD) {
        const int h2 = g >> 6, d2 = g & 63;
        float rz = 0.f;
        for (int cb = 0; cb < NCHUNK; cb += 16) {
            float w[16];
#pragma unroll
            for (int u = 0; u < 16; ++u)
                w[u] = zc[((size_t)(h2 * NCHUNK + cb + u)) * HD + d2];
#pragma unroll
            for (int u = 0; u < 16; ++u) {
                S0b[((size_t)((h2 * NCHUNK + cb + u) * 65 + 64)) * 64 + d2] = f2bf(rz);
                rz += w[u];
            }
        }
    }
}

// ---------------------------------------------------------------------------
// K4: per-(head,chunk) intra-chunk attention — Q,K,V staged in LDS (R5, passed)
// ---------------------------------------------------------------------------
__global__ __launch_bounds__(256)
void chunk_attn(const short* __restrict__ Qb, const short* __restrict__ Kb,
                const short* __restrict__ Vb, const short* __restrict__ S0b,
                short* __restrict__ attn)
{
    __shared__ __align__(16) short Vs[65 * SP];   // V^T, row 64 = ones
    __shared__ __align__(16) short Ks[64 * SP];   // K rows (l x d)
    __shared__ __align__(16) short Qs[64 * SP];   // Q rows (l x d)
    __shared__ __align__(16) short As[64 * SP];
    const int c = blockIdx.x, h = blockIdx.y;
    const int tid = threadIdx.x, lane = tid & 63, wave = tid >> 6;
    const size_t rb = ((size_t)h * L_SEQ + (size_t)c * CHUNK) * HD;
    const short* Qg = Qb + rb;
    const short* Kg = Kb + rb;
    const short* Vg = Vb + rb;
    const short* Sg = S0b + (size_t)(h * NCHUNK + c) * 65 * 64;

#pragma unroll
    for (int q = 0; q < 2; ++q) {
        const int idx = q * 256 + tid;
        const int row = idx >> 3, c8 = (idx & 7) << 3;
        const bf16x8 vv = *(const bf16x8*)&Vg[row * 64 + c8];
        const bf16x8 kk = *(const bf16x8*)&Kg[row * 64 + c8];
        const bf16x8 qq = *(const bf16x8*)&Qg[row * 64 + c8];
#pragma unroll
        for (int j = 0; j < 8; ++j) Vs[(c8 + j) * SP + row] = vv[j];   // V^T
        *(bf16x8*)&Ks[row * SP + c8] = kk;                             // K rows
        *(bf16x8*)&Qs[row * SP + c8] = qq;                             // Q rows
    }
    if (tid < 64) Vs[64 * SP + tid] = (short)0x3F80;                   // ones
    __syncthreads();

    const int frow = lane & 15;
    const int quad = lane >> 4;
    const int fko  = quad << 3;
    const int wm   = wave << 4;

    const bf16x8 qf0 = *(const bf16x8*)&Qs[(wm + frow) * SP + fko];
    const bf16x8 qf1 = *(const bf16x8*)&Qs[(wm + frow) * SP + 32 + fko];

    floatx4 sacc[4] = {};
#pragma unroll
    for (int n = 0; n < 4; ++n) {
        const bf16x8 kf0 = *(const bf16x8*)&Ks[(n * 16 + frow) * SP + fko];
        const bf16x8 kf1 = *(const bf16x8*)&Ks[(n * 16 + frow) * SP + 32 + fko];
        sacc[n] = MFMA16(qf0, kf0, sacc[n], 0, 0, 0);
        sacc[n] = MFMA16(qf1, kf1, sacc[n], 0, 0, 0);
    }
#pragma unroll
    for (int n = 0; n < 4; ++n)
#pragma unroll
        for (int r = 0; r < 4; ++r) {
            const int i = wm + quad * 4 + r;
            const int j = n * 16 + frow;
            As[i * SP + j] = (j <= i) ? f2bf(sacc[n][r]) : (short)0;
        }
    const bf16x8 af0 = *(const bf16x8*)&As[(wm + frow) * SP + fko];
    const bf16x8 af1 = *(const bf16x8*)&As[(wm + frow) * SP + 32 + fko];

    floatx4 oacc[5] = {};
#pragma unroll
    for (int n = 0; n < 4; ++n) {
        const bf16x8 vf0 = *(const bf16x8*)&Vs[(n * 16 + frow) * SP + fko];
        const bf16x8 vf1 = *(const bf16x8*)&Vs[(n * 16 + frow) * SP + 32 + fko];
        oacc[n] = MFMA16(af0, vf0, oacc[n], 0, 0, 0);
        oacc[n] = MFMA16(af1, vf1, oacc[n], 0, 0, 0);
        const bf16x8 sf0 = *(const bf16x8*)&Sg[(n * 16 + frow) * 64 + fko];
        const bf16x8 sf1 = *(const bf16x8*)&Sg[(n * 16 + frow) * 64 + 32 + fko];
        oacc[n] = MFMA16(qf0, sf0, oacc[n], 0, 0, 0);
        oacc[n] = MFMA16(qf1, sf1, oacc[n], 0, 0, 0);
    }
    {   // tile 4: broadcast row 64 (ones / z0) -> col 64 = norm
        const bf16x8 vf0 = *(const bf16x8*)&Vs[64 * SP + fko];
        const bf16x8 vf1 = *(const bf16x8*)&Vs[64 * SP + 32 + fko];
        oacc[4] = MFMA16(af0, vf0, oacc[4], 0, 0, 0);
        oacc[4] = MFMA16(af1, vf1, oacc[4], 0, 0, 0);
        const bf16x8 sf0 = *(const bf16x8*)&Sg[64 * 64 + fko];
        const bf16x8 sf1 = *(const bf16x8*)&Sg[64 * 64 + 32 + fko];
        oacc[4] = MFMA16(qf0, sf0, oacc[4], 0, 0, 0);
        oacc[4] = MFMA16(qf1, sf1, oacc[4], 0, 0, 0);
    }
#pragma unroll
    for (int r = 0; r < 4; ++r) {
        const float norm = __shfl(oacc[4][r], lane & 48) + EPS;
        const float inv = 1.f / norm;
        const int i = wm + quad * 4 + r;
#pragma unroll
        for (int n = 0; n < 4; ++n)
            As[i * SP + n * 16 + frow] = f2bf(oacc[n][r] * inv);
    }
    __syncthreads();
#pragma unroll
    for (int t = 0; t < 2; ++t) {
        const int idx = t * 256 + tid;
        const int row = idx >> 3, c8 = (idx & 7) << 3;
        *(bf16x8*)&attn[(size_t)(c * CHUNK + row) * EMB + h * HD + c8] =
            *(const bf16x8*)&As[row * SP + c8];
    }
}

// ---------------------------------------------------------------------------
extern "C" void kernel_launch(void* const* d_in, const int* in_sizes, int n_in,
                              void* d_out, int out_size, void* d_ws, size_t ws_size,
                              hipStream_t stream)
{
    const float* x     = (const float*)d_in[0];
    const float* qkv_w = (const float*)d_in[1];
    const float* qkv_b = (const float*)d_in[2];
    const float* out_w = (const float*)d_in[3];
    const float* out_b = (const float*)d_in[4];
    float* out = (float*)d_out;

    short* ws    = (short*)d_ws;
    short* Qb    = ws;                   // head-major bf16, 4194304 each
    short* Kb    = Qb + 4194304;
    short* Vb    = Kb + 4194304;
    short* xb    = Vb + 4194304;
    short* qwt   = xb + 4194304;         // 3072 x 1024
    short* owt   = qwt + 3145728;        // 1024 x 1024
    short* attnb = owt + 1048576;        // 4096 x 1024
    short* ScTb  = attnb + 4194304;      // 1024 * 64 * 64
    short* S0b   = ScTb + 4194304;       // 1024 * 65 * 64
    float* zc    = (float*)(S0b + 4259840);    // 65536 fp32

    prep<<<dim3(3072), 256, 0, stream>>>(x, xb, qkv_w, qwt, out_w, owt);
    mfma_gemm_qkv256<<<dim3(16, 32), 256, 0, stream>>>(
        xb, qwt, qkv_b, Qb, Kb, Vb);
    chunk_state<<<dim3(NCHUNK, NH), 256, 0, stream>>>(Kb, Vb, ScTb, zc);
    prefix_scan<<<dim3((NH * 4096) / 256), 256, 0, stream>>>(ScTb, zc, S0b);
    chunk_attn<<<dim3(NCHUNK, NH), 256, 0, stream>>>(Qb, Kb, Vb, S0b, attnb);
    mfma_gemm_out<<<dim3(EMB / 128, L_SEQ / 64), 256, 0, stream>>>(
        attnb, owt, out_b, out, EMB, EMB);
}

// Round 9
// 152.714 us; speedup vs baseline: 1.0276x; 1.0276x over previous
//
#include <hip/hip_runtime.h>
#include <cstddef>
#include <cstdint>

#define L_SEQ 4096
#define EMB   1024
#define NH    16
#define HD    64
#define N3    3072
#define CHUNK 64
#define NCHUNK 64
#define EPS 1e-6f

typedef __attribute__((ext_vector_type(8))) short   bf16x8;
typedef __attribute__((ext_vector_type(4))) short   bf16x4;
typedef __attribute__((ext_vector_type(4))) float   floatx4;

#define AS1 __attribute__((address_space(1)))
#define AS3 __attribute__((address_space(3)))

__device__ __forceinline__ void gload_lds16(const void* g, void* l) {
    __builtin_amdgcn_global_load_lds((AS1 const unsigned int*)g,
                                     (AS3 unsigned int*)l, 16, 0, 0);
}

// round-to-nearest-even fp32 -> bf16 bits
__device__ __forceinline__ short f2bf(float f) {
    union { float f; unsigned u; } a; a.f = f;
    unsigned r = a.u + 0x7fffu + ((a.u >> 16) & 1u);
    return (short)(r >> 16);
}
__device__ __forceinline__ float bf2f(short s) {
    union { unsigned u; float f; } a; a.u = ((unsigned)(unsigned short)s) << 16;
    return a.f;
}

// ---------------------------------------------------------------------------
// K0: fused prep — blocks [0,2048): x->bf16; [2048,2816): qkv_w^T;
// [2816,3072): out_w^T.
// ---------------------------------------------------------------------------
__device__ __forceinline__ void transpose_tile(const float* __restrict__ W,
                                               short* __restrict__ WT,
                                               int K, int N, int bx, int by,
                                               float (*t)[65], int tid)
{
    const int r  = tid >> 4;
    const int c4 = (tid & 15) << 2;
#pragma unroll
    for (int s = 0; s < 4; ++s) {
        const int k = r + s * 16;
        const floatx4 v = *(const floatx4*)&W[(size_t)(by * 64 + k) * N + bx * 64 + c4];
        t[k][c4 + 0] = v[0]; t[k][c4 + 1] = v[1];
        t[k][c4 + 2] = v[2]; t[k][c4 + 3] = v[3];
    }
    __syncthreads();
#pragma unroll
    for (int s = 0; s < 4; ++s) {
        const int n = r + s * 16;
        bf16x4 o;
        o[0] = f2bf(t[c4 + 0][n]); o[1] = f2bf(t[c4 + 1][n]);
        o[2] = f2bf(t[c4 + 2][n]); o[3] = f2bf(t[c4 + 3][n]);
        *(bf16x4*)&WT[(size_t)(bx * 64 + n) * K + by * 64 + c4] = o;
    }
}

__global__ __launch_bounds__(256)
void prep(const float* __restrict__ x, short* __restrict__ xb,
          const float* __restrict__ qkv_w, short* __restrict__ qwt,
          const float* __restrict__ out_w, short* __restrict__ owt)
{
    __shared__ float t[64][65];
    const int b = blockIdx.x;
    const int tid = threadIdx.x;
    if (b < 2048) {
        const int i = b * 256 + tid;
        const floatx4 a = *(const floatx4*)(x + (size_t)i * 8);
        const floatx4 c = *(const floatx4*)(x + (size_t)i * 8 + 4);
        bf16x8 o;
        o[0] = f2bf(a[0]); o[1] = f2bf(a[1]); o[2] = f2bf(a[2]); o[3] = f2bf(a[3]);
        o[4] = f2bf(c[0]); o[5] = f2bf(c[1]); o[6] = f2bf(c[2]); o[7] = f2bf(c[3]);
        *(bf16x8*)(xb + (size_t)i * 8) = o;
    } else if (b < 2048 + 768) {
        const int u = b - 2048;
        transpose_tile(qkv_w, qwt, EMB, N3, u % 48, u / 48, t, tid);
    } else {
        const int u = b - 2816;
        transpose_tile(out_w, owt, EMB, EMB, u & 15, u >> 4, t, tid);
    }
}

// ---------------------------------------------------------------------------
// K1: qkv GEMM — 128x192 tile, 256 threads, 2 blocks/CU, 8-phase (R8, passed)
// ---------------------------------------------------------------------------
#define MFMA16 __builtin_amdgcn_mfma_f32_16x16x32_bf16

__global__ __launch_bounds__(256, 2)
void mfma_gemm_qkv256(const short* __restrict__ A, const short* __restrict__ BT,
                      const float* __restrict__ bias,
                      short* __restrict__ OQ, short* __restrict__ OK,
                      short* __restrict__ OV)
{
    __shared__ __align__(16) short lds[40960];   // 80 KiB
    const int tid  = threadIdx.x;
    const int lane = tid & 63;
    const int wave = tid >> 6;           // 0..3
    const int wc   = wave;               // N quarter, 48 cols each
    const int frow = lane & 15;
    const int quad = lane >> 4;
    const int q8   = quad * 8;
    const int fid = blockIdx.y * 16 + blockIdx.x;      // 0..511
    const int xg  = fid & 7;
    const int j   = fid >> 3;                          // 0..63
    const int bx  = (xg & 1) * 8 + (j & 7);            // 0..15 (192 cols)
    const int by  = (xg >> 1) * 8 + (j >> 3);          // 0..31 (128 rows)

    const short* Ab = A  + (size_t)(by * 128) * 1024;
    const short* Bb = BT + (size_t)(bx * 192) * 1024;

    const int trow = tid >> 3;                       // 0..31
    const int ccol = (tid & 7) * 8;                  // dst col chunk, shorts
    const int scol = ccol ^ ((trow & 14) << 2);      // 3-bit swizzled src col
    const int sx   = (frow & 14) << 2;               // read-side XOR, shorts
    const int wcb  = wc * 48 + frow;                 // B fragment row base

#define STG_A(LBASE, GPTR) do {                                             \
        const short* g_ = (GPTR);                                           \
        _Pragma("unroll")                                                   \
        for (int j_ = 0; j_ < 4; ++j_) {                                    \
            const int r_ = j_ * 32 + trow;                                  \
            gload_lds16(g_ + (size_t)r_ * 1024 + scol,                      \
                        &lds[(LBASE) + r_ * 64 + ccol]);                    \
        }                                                                   \
    } while (0)

#define STG_B(LBASE, GPTR) do {                                             \
        const short* g_ = (GPTR);                                           \
        _Pragma("unroll")                                                   \
        for (int j_ = 0; j_ < 6; ++j_) {                                    \
            const int r_ = j_ * 32 + trow;                                  \
            gload_lds16(g_ + (size_t)r_ * 1024 + scol,                      \
                        &lds[(LBASE) + r_ * 64 + ccol]);                    \
        }                                                                   \
    } while (0)

#define LDA(BASE, R, KS) \
    (*(const bf16x8*)&lds[(BASE) + (R) * 64 + ((((KS) * 32) + q8) ^ sx)])

    floatx4 acc[8][3] = {};
    bf16x8  bq[3][2];

#define PHASE(ABASE, BBASE, QD, RDB, VM, ...) do {                          \
        const int Rr_ = (QD) * 32 + frow;                                   \
        bf16x8 a0_ = LDA((ABASE), Rr_,      0);                             \
        bf16x8 a1_ = LDA((ABASE), Rr_,      1);                             \
        bf16x8 a2_ = LDA((ABASE), Rr_ + 16, 0);                             \
        bf16x8 a3_ = LDA((ABASE), Rr_ + 16, 1);                             \
        if (RDB) {                                                          \
            _Pragma("unroll")                                               \
            for (int ni_ = 0; ni_ < 3; ++ni_) {                             \
                bq[ni_][0] = LDA((BBASE), wcb + ni_ * 16, 0);               \
                bq[ni_][1] = LDA((BBASE), wcb + ni_ * 16, 1);               \
            }                                                               \
        }                                                                   \
        __VA_ARGS__;                                                        \
        __builtin_amdgcn_sched_barrier(0);                                  \
        __builtin_amdgcn_s_barrier();                                       \
        asm volatile("s_waitcnt lgkmcnt(0)" ::: "memory");                  \
        __builtin_amdgcn_sched_barrier(0);                                  \
        __builtin_amdgcn_s_setprio(1);                                      \
        _Pragma("unroll")                                                   \
        for (int ni_ = 0; ni_ < 3; ++ni_) {                                 \
            acc[2*(QD)  ][ni_] = MFMA16(a0_, bq[ni_][0], acc[2*(QD)  ][ni_], 0,0,0); \
            acc[2*(QD)  ][ni_] = MFMA16(a1_, bq[ni_][1], acc[2*(QD)  ][ni_], 0,0,0); \
            acc[2*(QD)+1][ni_] = MFMA16(a2_, bq[ni_][0], acc[2*(QD)+1][ni_], 0,0,0); \
            acc[2*(QD)+1][ni_] = MFMA16(a3_, bq[ni_][1], acc[2*(QD)+1][ni_], 0,0,0); \
        }                                                                   \
        __builtin_amdgcn_s_setprio(0);                                      \
        if (VM) asm volatile("s_waitcnt vmcnt(6)" ::: "memory");            \
        __builtin_amdgcn_s_barrier();                                       \
        __builtin_amdgcn_sched_barrier(0);                                  \
    } while (0)

    STG_A(0,     Ab);                    // buf0.A (t0)
    STG_B(8192,  Bb);                    // buf0.B (t0)
    STG_B(28672, Bb + 64);               // buf1.B (t1)
    asm volatile("s_waitcnt vmcnt(6)" ::: "memory");
    __builtin_amdgcn_s_barrier();
    __builtin_amdgcn_sched_barrier(0);

#pragma unroll 1
    for (int it = 0; it < 8; ++it) {
        const int k1  = (2 * it + 1) * 64;             // odd tile k-offset
        const int kn0 = ((2 * it + 2) & 15) * 64;      // next even (wrapped)
        const int kn1 = ((2 * it + 3) & 15) * 64;      // next odd (wrapped)

        PHASE(0, 8192, 0, 1, 0, STG_A(20480, Ab + k1));
        PHASE(0, 8192, 1, 0, 0, STG_B(8192, Bb + kn0));
        PHASE(0, 8192, 2, 0, 0, ((void)0));
        PHASE(0, 8192, 3, 0, 1, ((void)0));
        PHASE(20480, 28672, 0, 1, 0, STG_A(0, Ab + kn0));
        PHASE(20480, 28672, 1, 0, 0, ((void)0));
        PHASE(20480, 28672, 2, 0, 0, STG_B(28672, Bb + kn1));
        PHASE(20480, 28672, 3, 0, 1, ((void)0));
    }

    __syncthreads();

    const int wbase = wave * 6144;
    const int colg0 = bx * 192 + wc * 48;
    const int L0 = by * 128;
#pragma unroll
    for (int ni = 0; ni < 3; ++ni) {
        const int n = colg0 + ni * 16 + frow;
        const float bv = bias[n];
        const bool do_elu = (n >> 10) < 2;
#pragma unroll
        for (int mi = 0; mi < 8; ++mi)
#pragma unroll
            for (int r = 0; r < 4; ++r) {
                float v = acc[mi][ni][r] + bv;
                if (do_elu) v = (v > 0.f) ? (v + 1.f) : __expf(v);
                lds[wbase + (mi * 16 + quad * 4 + r) * 48 + ni * 16 + frow] = f2bf(v);
            }
    }
#pragma unroll
    for (int s = 0; s < 12; ++s) {
        const int chunk = s * 64 + lane;     // 768 chunks of 8 shorts
        const int row = chunk / 6, cc = (chunk % 6) * 8;
        const bf16x8 val = *(const bf16x8*)&lds[wbase + row * 48 + cc];
        const int n0 = colg0 + cc;
        const int rsel = n0 >> 10;
        const int h = (n0 & 1023) >> 6;
        const int d = n0 & 63;
        short* base = (rsel == 0) ? OQ : (rsel == 1 ? OK : OV);
        *(bf16x8*)&base[((size_t)(h * L_SEQ + L0 + row)) * HD + d] = val;
    }
#undef PHASE
#undef LDA
#undef STG_A
#undef STG_B
}

// ---------------------------------------------------------------------------
// K5: out-projection GEMM — R9: 2-phase double-buffered staging (T3 minimum
// recipe): next tile's 6 global_load_lds issued BEFORE current tile's
// ds_read+MFMA; single vmcnt(0)+barrier per tile. The old structure drained
// all loads at a barrier before any MFMA (zero overlap).
// LDS 48 KB (buf0 @0: A 4096 + B 8192 shorts; buf1 @12288) -> 2 blocks/CU.
// ---------------------------------------------------------------------------
__global__ __launch_bounds__(256)
void mfma_gemm_out(const short* __restrict__ A, const short* __restrict__ BT,
                   const float* __restrict__ bias, float* __restrict__ OF,
                   int N, int K)
{
    __shared__ __align__(16) short smem[24576];
    const int tid  = threadIdx.x;
    const int lane = tid & 63;
    const int wave = tid >> 6;
    const int wm = (wave >> 1) * 32;
    const int wn = (wave & 1) * 64;
    const int fid = blockIdx.y * 8 + blockIdx.x;
    const int nf  = (fid & 7) * 64 + (fid >> 3);
    const int bx  = nf & 7;
    const int by  = nf >> 3;
    const int frow = lane & 15;
    const int quad = lane >> 4;
    const int q8   = quad << 3;
    const int sx   = (frow & 14) << 2;

    const short* Ab = A  + (size_t)(by * 64) * K;
    const short* Bb = BT + (size_t)(bx * 128) * K;

#define OSTG(BASE, KOFF) do {                                               \
        _Pragma("unroll")                                                   \
        for (int q_ = 0; q_ < 2; ++q_) {                                    \
            const int idx_ = q_ * 256 + tid;                                \
            const int row_ = idx_ >> 3;                                     \
            const int c8_  = (idx_ & 7) << 3;                               \
            gload_lds16(Ab + (size_t)row_ * K + (KOFF) + (c8_ ^ ((row_ & 14) << 2)), \
                        &smem[(BASE) + (idx_ << 3)]);                       \
        }                                                                   \
        _Pragma("unroll")                                                   \
        for (int q_ = 0; q_ < 4; ++q_) {                                    \
            const int idx_ = q_ * 256 + tid;                                \
            const int row_ = idx_ >> 3;                                     \
            const int c8_  = (idx_ & 7) << 3;                               \
            gload_lds16(Bb + (size_t)row_ * K + (KOFF) + (c8_ ^ ((row_ & 14) << 2)), \
                        &smem[(BASE) + 4096 + (idx_ << 3)]);                \
        }                                                                   \
    } while (0)

#define OCOMP(BASE) do {                                                    \
        bf16x8 af_[2][2], bfv_[4][2];                                       \
        _Pragma("unroll")                                                   \
        for (int mi_ = 0; mi_ < 2; ++mi_)                                   \
            _Pragma("unroll")                                               \
            for (int ks_ = 0; ks_ < 2; ++ks_)                               \
                af_[mi_][ks_] = *(const bf16x8*)                            \
                    &smem[(BASE) + (wm + mi_ * 16 + frow) * 64 + ((ks_ * 32 + q8) ^ sx)]; \
        _Pragma("unroll")                                                   \
        for (int ni_ = 0; ni_ < 4; ++ni_)                                   \
            _Pragma("unroll")                                               \
            for (int ks_ = 0; ks_ < 2; ++ks_)                               \
                bfv_[ni_][ks_] = *(const bf16x8*)                           \
                    &smem[(BASE) + 4096 + (wn + ni_ * 16 + frow) * 64 + ((ks_ * 32 + q8) ^ sx)]; \
        _Pragma("unroll")                                                   \
        for (int mi_ = 0; mi_ < 2; ++mi_)                                   \
            _Pragma("unroll")                                               \
            for (int ni_ = 0; ni_ < 4; ++ni_) {                             \
                acc[mi_][ni_] = MFMA16(af_[mi_][0], bfv_[ni_][0], acc[mi_][ni_], 0, 0, 0); \
                acc[mi_][ni_] = MFMA16(af_[mi_][1], bfv_[ni_][1], acc[mi_][ni_], 0, 0, 0); \
            }                                                               \
        __builtin_amdgcn_sched_barrier(0);                                  \
        asm volatile("s_waitcnt vmcnt(0)" ::: "memory");                    \
        __builtin_amdgcn_s_barrier();                                       \
        __builtin_amdgcn_sched_barrier(0);                                  \
    } while (0)

    floatx4 acc[2][4] = {};

    OSTG(0, 0);
    asm volatile("s_waitcnt vmcnt(0)" ::: "memory");
    __builtin_amdgcn_s_barrier();
    __builtin_amdgcn_sched_barrier(0);

#pragma unroll 1
    for (int it = 0; it < 8; ++it) {
        const int k1 = (2 * it + 1) * 64;              // odd tile
        const int kn = ((2 * it + 2) & 15) * 64;       // next even (wrapped)
        OSTG(12288, k1);        // stage odd tile into buf1
        OCOMP(0);               // compute even tile from buf0
        OSTG(0, kn);            // stage next even into buf0 (wrapped at it=7)
        OCOMP(12288);           // compute odd tile from buf1
    }

    const int rq = quad << 2;
#pragma unroll
    for (int ni = 0; ni < 4; ++ni) {
        const int n = bx * 128 + wn + ni * 16 + frow;
        const float bv = bias[n];
#pragma unroll
        for (int mi = 0; mi < 2; ++mi)
#pragma unroll
            for (int r = 0; r < 4; ++r) {
                const int m = by * 64 + wm + mi * 16 + rq + r;
                OF[(size_t)m * N + n] = acc[mi][ni][r] + bv;
            }
    }
#undef OSTG
#undef OCOMP
}

// ---------------------------------------------------------------------------
// K2: per-(head,chunk) state sums, MFMA version. (unchanged, passed)
// ---------------------------------------------------------------------------
#define SP 72

__global__ __launch_bounds__(256, 4)
void chunk_state(const short* __restrict__ Kb, const short* __restrict__ Vb,
                 short* __restrict__ ScTb, float* __restrict__ zc)
{
    __shared__ __align__(16) short Vt[64 * SP];   // V^T: rows e, cols l
    __shared__ __align__(16) short Kt[64 * SP];   // K'^T: rows d, cols l
    const int c = blockIdx.x, h = blockIdx.y;
    const int tid = threadIdx.x, lane = tid & 63, wave = tid >> 6;
    const int frow = lane & 15;
    const int quad = lane >> 4;
    const int fko  = quad << 3;
    const int wm   = wave << 4;
    const short* Kg = Kb + ((size_t)h * L_SEQ + (size_t)c * CHUNK) * HD;
    const short* Vg = Vb + ((size_t)h * L_SEQ + (size_t)c * CHUNK) * HD;

#pragma unroll
    for (int q = 0; q < 2; ++q) {
        const int idx = q * 256 + tid;            // 512 chunks of 8
        const int l = idx >> 3, c8 = (idx & 7) << 3;
        const bf16x8 vv = *(const bf16x8*)&Vg[l * 64 + c8];
        const bf16x8 kk = *(const bf16x8*)&Kg[l * 64 + c8];
#pragma unroll
        for (int j = 0; j < 8; ++j) {
            Vt[(c8 + j) * SP + l] = vv[j];
            Kt[(c8 + j) * SP + l] = kk[j];
        }
    }
    __syncthreads();

    const bf16x8 af0 = *(const bf16x8*)&Vt[(wm + frow) * SP + fko];
    const bf16x8 af1 = *(const bf16x8*)&Vt[(wm + frow) * SP + 32 + fko];

    floatx4 acc[4] = {};
#pragma unroll
    for (int n = 0; n < 4; ++n) {
        const bf16x8 kf0 = *(const bf16x8*)&Kt[(n * 16 + frow) * SP + fko];
        const bf16x8 kf1 = *(const bf16x8*)&Kt[(n * 16 + frow) * SP + 32 + fko];
        acc[n] = MFMA16(af0, kf0, acc[n], 0, 0, 0);
        acc[n] = MFMA16(af1, kf1, acc[n], 0, 0, 0);
    }

    short* Sout = ScTb + (size_t)(h * NCHUNK + c) * 4096;
#pragma unroll
    for (int n = 0; n < 4; ++n)
#pragma unroll
        for (int r = 0; r < 4; ++r) {
            const int e = wm + quad * 4 + r;
            const int d = n * 16 + frow;
            Sout[e * 64 + d] = f2bf(acc[n][r]);
        }

    if (wave == 0) {   // z[d] = sum_l K'[l][d] via all-ones A fragment
        bf16x8 ones;
#pragma unroll
        for (int j = 0; j < 8; ++j) ones[j] = (short)0x3F80;
        floatx4 zacc[4] = {};
#pragma unroll
        for (int n = 0; n < 4; ++n) {
            const bf16x8 kf0 = *(const bf16x8*)&Kt[(n * 16 + frow) * SP + fko];
            const bf16x8 kf1 = *(const bf16x8*)&Kt[(n * 16 + frow) * SP + 32 + fko];
            zacc[n] = MFMA16(ones, kf0, zacc[n], 0, 0, 0);
            zacc[n] = MFMA16(ones, kf1, zacc[n], 0, 0, 0);
        }
        if (quad == 0) {
#pragma unroll
            for (int n = 0; n < 4; ++n)
                zc[(size_t)(h * NCHUNK + c) * 64 + n * 16 + frow] = zacc[n][0];
        }
    }
}

// ---------------------------------------------------------------------------
// K3: exclusive prefix over chunks, 16-deep batches. (R7, passed)
// ---------------------------------------------------------------------------
__global__ __launch_bounds__(256)
void prefix_scan(const short* __restrict__ ScTb, const float* __restrict__ zc,
                 short* __restrict__ S0b)
{
    const int g = blockIdx.x * 256 + threadIdx.x;
    const int h  = g >> 12;
    const int ed = g & 4095;
    const int e  = ed >> 6;
    const int d  = ed & 63;
    const short* src = ScTb + (size_t)h * NCHUNK * 4096 + ed;
    float run = 0.f;
    for (int cb = 0; cb < NCHUNK; cb += 16) {
        short v[16];
#pragma unroll
        for (int u = 0; u < 16; ++u) v[u] = src[(size_t)(cb + u) * 4096];
#pragma unroll
        for (int u = 0; u < 16; ++u) {
            S0b[((size_t)((h * NCHUNK + cb + u) * 65 + e)) * 64 + d] = f2bf(run);
            run += bf2f(v[u]);
        }
    }
    if (g < NH * HD) {
        const int h2 = g >> 6, d2 = g & 63;
        float rz = 0.f;
        for (int cb = 0; cb < NCHUNK; cb += 16) {
            float w[16];
#pragma unroll
            for (int u = 0; u < 16; ++u)
                w[u] = zc[((size_t)(h2 * NCHUNK + cb + u)) * HD + d2];
#pragma unroll
            for (int u = 0; u < 16; ++u) {
                S0b[((size_t)((h2 * NCHUNK + cb + u) * 65 + 64)) * 64 + d2] = f2bf(rz);
                rz += w[u];
            }
        }
    }
}

// ---------------------------------------------------------------------------
// K4: per-(head,chunk) intra-chunk attention — Q,K,V staged in LDS (R5, passed)
// ---------------------------------------------------------------------------
__global__ __launch_bounds__(256)
void chunk_attn(const short* __restrict__ Qb, const short* __restrict__ Kb,
                const short* __restrict__ Vb, const short* __restrict__ S0b,
                short* __restrict__ attn)
{
    __shared__ __align__(16) short Vs[65 * SP];   // V^T, row 64 = ones
    __shared__ __align__(16) short Ks[64 * SP];   // K rows (l x d)
    __shared__ __align__(16) short Qs[64 * SP];   // Q rows (l x d)
    __shared__ __align__(16) short As[64 * SP];
    const int c = blockIdx.x, h = blockIdx.y;
    const int tid = threadIdx.x, lane = tid & 63, wave = tid >> 6;
    const size_t rb = ((size_t)h * L_SEQ + (size_t)c * CHUNK) * HD;
    const short* Qg = Qb + rb;
    const short* Kg = Kb + rb;
    const short* Vg = Vb + rb;
    const short* Sg = S0b + (size_t)(h * NCHUNK + c) * 65 * 64;

#pragma unroll
    for (int q = 0; q < 2; ++q) {
        const int idx = q * 256 + tid;
        const int row = idx >> 3, c8 = (idx & 7) << 3;
        const bf16x8 vv = *(const bf16x8*)&Vg[row * 64 + c8];
        const bf16x8 kk = *(const bf16x8*)&Kg[row * 64 + c8];
        const bf16x8 qq = *(const bf16x8*)&Qg[row * 64 + c8];
#pragma unroll
        for (int j = 0; j < 8; ++j) Vs[(c8 + j) * SP + row] = vv[j];   // V^T
        *(bf16x8*)&Ks[row * SP + c8] = kk;                             // K rows
        *(bf16x8*)&Qs[row * SP + c8] = qq;                             // Q rows
    }
    if (tid < 64) Vs[64 * SP + tid] = (short)0x3F80;                   // ones
    __syncthreads();

    const int frow = lane & 15;
    const int quad = lane >> 4;
    const int fko  = quad << 3;
    const int wm   = wave << 4;

    const bf16x8 qf0 = *(const bf16x8*)&Qs[(wm + frow) * SP + fko];
    const bf16x8 qf1 = *(const bf16x8*)&Qs[(wm + frow) * SP + 32 + fko];

    floatx4 sacc[4] = {};
#pragma unroll
    for (int n = 0; n < 4; ++n) {
        const bf16x8 kf0 = *(const bf16x8*)&Ks[(n * 16 + frow) * SP + fko];
        const bf16x8 kf1 = *(const bf16x8*)&Ks[(n * 16 + frow) * SP + 32 + fko];
        sacc[n] = MFMA16(qf0, kf0, sacc[n], 0, 0, 0);
        sacc[n] = MFMA16(qf1, kf1, sacc[n], 0, 0, 0);
    }
#pragma unroll
    for (int n = 0; n < 4; ++n)
#pragma unroll
        for (int r = 0; r < 4; ++r) {
            const int i = wm + quad * 4 + r;
            const int j = n * 16 + frow;
            As[i * SP + j] = (j <= i) ? f2bf(sacc[n][r]) : (short)0;
        }
    const bf16x8 af0 = *(const bf16x8*)&As[(wm + frow) * SP + fko];
    const bf16x8 af1 = *(const bf16x8*)&As[(wm + frow) * SP + 32 + fko];

    floatx4 oacc[5] = {};
#pragma unroll
    for (int n = 0; n < 4; ++n) {
        const bf16x8 vf0 = *(const bf16x8*)&Vs[(n * 16 + frow) * SP + fko];
        const bf16x8 vf1 = *(const bf16x8*)&Vs[(n * 16 + frow) * SP + 32 + fko];
        oacc[n] = MFMA16(af0, vf0, oacc[n], 0, 0, 0);
        oacc[n] = MFMA16(af1, vf1, oacc[n], 0, 0, 0);
        const bf16x8 sf0 = *(const bf16x8*)&Sg[(n * 16 + frow) * 64 + fko];
        const bf16x8 sf1 = *(const bf16x8*)&Sg[(n * 16 + frow) * 64 + 32 + fko];
        oacc[n] = MFMA16(qf0, sf0, oacc[n], 0, 0, 0);
        oacc[n] = MFMA16(qf1, sf1, oacc[n], 0, 0, 0);
    }
    {   // tile 4: broadcast row 64 (ones / z0) -> col 64 = norm
        const bf16x8 vf0 = *(const bf16x8*)&Vs[64 * SP + fko];
        const bf16x8 vf1 = *(const bf16x8*)&Vs[64 * SP + 32 + fko];
        oacc[4] = MFMA16(af0, vf0, oacc[4], 0, 0, 0);
        oacc[4] = MFMA16(af1, vf1, oacc[4], 0, 0, 0);
        const bf16x8 sf0 = *(const bf16x8*)&Sg[64 * 64 + fko];
        const bf16x8 sf1 = *(const bf16x8*)&Sg[64 * 64 + 32 + fko];
        oacc[4] = MFMA16(qf0, sf0, oacc[4], 0, 0, 0);
        oacc[4] = MFMA16(qf1, sf1, oacc[4], 0, 0, 0);
    }
#pragma unroll
    for (int r = 0; r < 4; ++r) {
        const float norm = __shfl(oacc[4][r], lane & 48) + EPS;
        const float inv = 1.f / norm;
        const int i = wm + quad * 4 + r;
#pragma unroll
        for (int n = 0; n < 4; ++n)
            As[i * SP + n * 16 + frow] = f2bf(oacc[n][r] * inv);
    }
    __syncthreads();
#pragma unroll
    for (int t = 0; t < 2; ++t) {
        const int idx = t * 256 + tid;
        const int row = idx >> 3, c8 = (idx & 7) << 3;
        *(bf16x8*)&attn[(size_t)(c * CHUNK + row) * EMB + h * HD + c8] =
            *(const bf16x8*)&As[row * SP + c8];
    }
}

// ---------------------------------------------------------------------------
extern "C" void kernel_launch(void* const* d_in, const int* in_sizes, int n_in,
                              void* d_out, int out_size, void* d_ws, size_t ws_size,
                              hipStream_t stream)
{
    const float* x     = (const float*)d_in[0];
    const float* qkv_w = (const float*)d_in[1];
    const float* qkv_b = (const float*)d_in[2];
    const float* out_w = (const float*)d_in[3];
    const float* out_b = (const float*)d_in[4];
    float* out = (float*)d_out;

    short* ws    = (short*)d_ws;
    short* Qb    = ws;                   // head-major bf16, 4194304 each
    short* Kb    = Qb + 4194304;
    short* Vb    = Kb + 4194304;
    short* xb    = Vb + 4194304;
    short* qwt   = xb + 4194304;         // 3072 x 1024
    short* owt   = qwt + 3145728;        // 1024 x 1024
    short* attnb = owt + 1048576;        // 4096 x 1024
    short* ScTb  = attnb + 4194304;      // 1024 * 64 * 64
    short* S0b   = ScTb + 4194304;       // 1024 * 65 * 64
    float* zc    = (float*)(S0b + 4259840);    // 65536 fp32

    prep<<<dim3(3072), 256, 0, stream>>>(x, xb, qkv_w, qwt, out_w, owt);
    mfma_gemm_qkv256<<<dim3(16, 32), 256, 0, stream>>>(
        xb, qwt, qkv_b, Qb, Kb, Vb);
    chunk_state<<<dim3(NCHUNK, NH), 256, 0, stream>>>(Kb, Vb, ScTb, zc);
    prefix_scan<<<dim3((NH * 4096) / 256), 256, 0, stream>>>(ScTb, zc, S0b);
    chunk_attn<<<dim3(NCHUNK, NH), 256, 0, stream>>>(Qb, Kb, Vb, S0b, attnb);
    mfma_gemm_out<<<dim3(EMB / 128, L_SEQ / 64), 256, 0, stream>>>(
        attnb, owt, out_b, out, EMB, EMB);
}

// Round 10
// 149.151 us; speedup vs baseline: 1.0521x; 1.0239x over previous
//
#include <hip/hip_runtime.h>
#include <cstddef>
#include <cstdint>

#define L_SEQ 4096
#define EMB   1024
#define NH    16
#define HD    64
#define N3    3072
#define CHUNK 64
#define NCHUNK 64
#define EPS 1e-6f

typedef __attribute__((ext_vector_type(8))) short   bf16x8;
typedef __attribute__((ext_vector_type(4))) short   bf16x4;
typedef __attribute__((ext_vector_type(4))) float   floatx4;

#define AS1 __attribute__((address_space(1)))
#define AS3 __attribute__((address_space(3)))

__device__ __forceinline__ void gload_lds16(const void* g, void* l) {
    __builtin_amdgcn_global_load_lds((AS1 const unsigned int*)g,
                                     (AS3 unsigned int*)l, 16, 0, 0);
}

// round-to-nearest-even fp32 -> bf16 bits
__device__ __forceinline__ short f2bf(float f) {
    union { float f; unsigned u; } a; a.f = f;
    unsigned r = a.u + 0x7fffu + ((a.u >> 16) & 1u);
    return (short)(r >> 16);
}
__device__ __forceinline__ float bf2f(short s) {
    union { unsigned u; float f; } a; a.u = ((unsigned)(unsigned short)s) << 16;
    return a.f;
}

// ---------------------------------------------------------------------------
// K0: fused prep — blocks [0,2048): x->bf16; [2048,2816): qkv_w^T;
// [2816,3072): out_w^T.
// ---------------------------------------------------------------------------
__device__ __forceinline__ void transpose_tile(const float* __restrict__ W,
                                               short* __restrict__ WT,
                                               int K, int N, int bx, int by,
                                               float (*t)[65], int tid)
{
    const int r  = tid >> 4;
    const int c4 = (tid & 15) << 2;
#pragma unroll
    for (int s = 0; s < 4; ++s) {
        const int k = r + s * 16;
        const floatx4 v = *(const floatx4*)&W[(size_t)(by * 64 + k) * N + bx * 64 + c4];
        t[k][c4 + 0] = v[0]; t[k][c4 + 1] = v[1];
        t[k][c4 + 2] = v[2]; t[k][c4 + 3] = v[3];
    }
    __syncthreads();
#pragma unroll
    for (int s = 0; s < 4; ++s) {
        const int n = r + s * 16;
        bf16x4 o;
        o[0] = f2bf(t[c4 + 0][n]); o[1] = f2bf(t[c4 + 1][n]);
        o[2] = f2bf(t[c4 + 2][n]); o[3] = f2bf(t[c4 + 3][n]);
        *(bf16x4*)&WT[(size_t)(bx * 64 + n) * K + by * 64 + c4] = o;
    }
}

__global__ __launch_bounds__(256)
void prep(const float* __restrict__ x, short* __restrict__ xb,
          const float* __restrict__ qkv_w, short* __restrict__ qwt,
          const float* __restrict__ out_w, short* __restrict__ owt)
{
    __shared__ float t[64][65];
    const int b = blockIdx.x;
    const int tid = threadIdx.x;
    if (b < 2048) {
        const int i = b * 256 + tid;
        const floatx4 a = *(const floatx4*)(x + (size_t)i * 8);
        const floatx4 c = *(const floatx4*)(x + (size_t)i * 8 + 4);
        bf16x8 o;
        o[0] = f2bf(a[0]); o[1] = f2bf(a[1]); o[2] = f2bf(a[2]); o[3] = f2bf(a[3]);
        o[4] = f2bf(c[0]); o[5] = f2bf(c[1]); o[6] = f2bf(c[2]); o[7] = f2bf(c[3]);
        *(bf16x8*)(xb + (size_t)i * 8) = o;
    } else if (b < 2048 + 768) {
        const int u = b - 2048;
        transpose_tile(qkv_w, qwt, EMB, N3, u % 48, u / 48, t, tid);
    } else {
        const int u = b - 2816;
        transpose_tile(out_w, owt, EMB, EMB, u & 15, u >> 4, t, tid);
    }
}

// ---------------------------------------------------------------------------
// K1: qkv GEMM — 128x192 tile, 256 threads, 2 blocks/CU, 8-phase (R8, passed)
// ---------------------------------------------------------------------------
#define MFMA16 __builtin_amdgcn_mfma_f32_16x16x32_bf16

__global__ __launch_bounds__(256, 2)
void mfma_gemm_qkv256(const short* __restrict__ A, const short* __restrict__ BT,
                      const float* __restrict__ bias,
                      short* __restrict__ OQ, short* __restrict__ OK,
                      short* __restrict__ OV)
{
    __shared__ __align__(16) short lds[40960];   // 80 KiB
    const int tid  = threadIdx.x;
    const int lane = tid & 63;
    const int wave = tid >> 6;           // 0..3
    const int wc   = wave;               // N quarter, 48 cols each
    const int frow = lane & 15;
    const int quad = lane >> 4;
    const int q8   = quad * 8;
    const int fid = blockIdx.y * 16 + blockIdx.x;      // 0..511
    const int xg  = fid & 7;
    const int j   = fid >> 3;                          // 0..63
    const int bx  = (xg & 1) * 8 + (j & 7);            // 0..15 (192 cols)
    const int by  = (xg >> 1) * 8 + (j >> 3);          // 0..31 (128 rows)

    const short* Ab = A  + (size_t)(by * 128) * 1024;
    const short* Bb = BT + (size_t)(bx * 192) * 1024;

    const int trow = tid >> 3;                       // 0..31
    const int ccol = (tid & 7) * 8;                  // dst col chunk, shorts
    const int scol = ccol ^ ((trow & 14) << 2);      // 3-bit swizzled src col
    const int sx   = (frow & 14) << 2;               // read-side XOR, shorts
    const int wcb  = wc * 48 + frow;                 // B fragment row base

#define STG_A(LBASE, GPTR) do {                                             \
        const short* g_ = (GPTR);                                           \
        _Pragma("unroll")                                                   \
        for (int j_ = 0; j_ < 4; ++j_) {                                    \
            const int r_ = j_ * 32 + trow;                                  \
            gload_lds16(g_ + (size_t)r_ * 1024 + scol,                      \
                        &lds[(LBASE) + r_ * 64 + ccol]);                    \
        }                                                                   \
    } while (0)

#define STG_B(LBASE, GPTR) do {                                             \
        const short* g_ = (GPTR);                                           \
        _Pragma("unroll")                                                   \
        for (int j_ = 0; j_ < 6; ++j_) {                                    \
            const int r_ = j_ * 32 + trow;                                  \
            gload_lds16(g_ + (size_t)r_ * 1024 + scol,                      \
                        &lds[(LBASE) + r_ * 64 + ccol]);                    \
        }                                                                   \
    } while (0)

#define LDA(BASE, R, KS) \
    (*(const bf16x8*)&lds[(BASE) + (R) * 64 + ((((KS) * 32) + q8) ^ sx)])

    floatx4 acc[8][3] = {};
    bf16x8  bq[3][2];

#define PHASE(ABASE, BBASE, QD, RDB, VM, ...) do {                          \
        const int Rr_ = (QD) * 32 + frow;                                   \
        bf16x8 a0_ = LDA((ABASE), Rr_,      0);                             \
        bf16x8 a1_ = LDA((ABASE), Rr_,      1);                             \
        bf16x8 a2_ = LDA((ABASE), Rr_ + 16, 0);                             \
        bf16x8 a3_ = LDA((ABASE), Rr_ + 16, 1);                             \
        if (RDB) {                                                          \
            _Pragma("unroll")                                               \
            for (int ni_ = 0; ni_ < 3; ++ni_) {                             \
                bq[ni_][0] = LDA((BBASE), wcb + ni_ * 16, 0);               \
                bq[ni_][1] = LDA((BBASE), wcb + ni_ * 16, 1);               \
            }                                                               \
        }                                                                   \
        __VA_ARGS__;                                                        \
        __builtin_amdgcn_sched_barrier(0);                                  \
        __builtin_amdgcn_s_barrier();                                       \
        asm volatile("s_waitcnt lgkmcnt(0)" ::: "memory");                  \
        __builtin_amdgcn_sched_barrier(0);                                  \
        __builtin_amdgcn_s_setprio(1);                                      \
        _Pragma("unroll")                                                   \
        for (int ni_ = 0; ni_ < 3; ++ni_) {                                 \
            acc[2*(QD)  ][ni_] = MFMA16(a0_, bq[ni_][0], acc[2*(QD)  ][ni_], 0,0,0); \
            acc[2*(QD)  ][ni_] = MFMA16(a1_, bq[ni_][1], acc[2*(QD)  ][ni_], 0,0,0); \
            acc[2*(QD)+1][ni_] = MFMA16(a2_, bq[ni_][0], acc[2*(QD)+1][ni_], 0,0,0); \
            acc[2*(QD)+1][ni_] = MFMA16(a3_, bq[ni_][1], acc[2*(QD)+1][ni_], 0,0,0); \
        }                                                                   \
        __builtin_amdgcn_s_setprio(0);                                      \
        if (VM) asm volatile("s_waitcnt vmcnt(6)" ::: "memory");            \
        __builtin_amdgcn_s_barrier();                                       \
        __builtin_amdgcn_sched_barrier(0);                                  \
    } while (0)

    STG_A(0,     Ab);                    // buf0.A (t0)
    STG_B(8192,  Bb);                    // buf0.B (t0)
    STG_B(28672, Bb + 64);               // buf1.B (t1)
    asm volatile("s_waitcnt vmcnt(6)" ::: "memory");
    __builtin_amdgcn_s_barrier();
    __builtin_amdgcn_sched_barrier(0);

#pragma unroll 1
    for (int it = 0; it < 8; ++it) {
        const int k1  = (2 * it + 1) * 64;             // odd tile k-offset
        const int kn0 = ((2 * it + 2) & 15) * 64;      // next even (wrapped)
        const int kn1 = ((2 * it + 3) & 15) * 64;      // next odd (wrapped)

        PHASE(0, 8192, 0, 1, 0, STG_A(20480, Ab + k1));
        PHASE(0, 8192, 1, 0, 0, STG_B(8192, Bb + kn0));
        PHASE(0, 8192, 2, 0, 0, ((void)0));
        PHASE(0, 8192, 3, 0, 1, ((void)0));
        PHASE(20480, 28672, 0, 1, 0, STG_A(0, Ab + kn0));
        PHASE(20480, 28672, 1, 0, 0, ((void)0));
        PHASE(20480, 28672, 2, 0, 0, STG_B(28672, Bb + kn1));
        PHASE(20480, 28672, 3, 0, 1, ((void)0));
    }

    __syncthreads();

    const int wbase = wave * 6144;
    const int colg0 = bx * 192 + wc * 48;
    const int L0 = by * 128;
#pragma unroll
    for (int ni = 0; ni < 3; ++ni) {
        const int n = colg0 + ni * 16 + frow;
        const float bv = bias[n];
        const bool do_elu = (n >> 10) < 2;
#pragma unroll
        for (int mi = 0; mi < 8; ++mi)
#pragma unroll
            for (int r = 0; r < 4; ++r) {
                float v = acc[mi][ni][r] + bv;
                if (do_elu) v = (v > 0.f) ? (v + 1.f) : __expf(v);
                lds[wbase + (mi * 16 + quad * 4 + r) * 48 + ni * 16 + frow] = f2bf(v);
            }
    }
#pragma unroll
    for (int s = 0; s < 12; ++s) {
        const int chunk = s * 64 + lane;     // 768 chunks of 8 shorts
        const int row = chunk / 6, cc = (chunk % 6) * 8;
        const bf16x8 val = *(const bf16x8*)&lds[wbase + row * 48 + cc];
        const int n0 = colg0 + cc;
        const int rsel = n0 >> 10;
        const int h = (n0 & 1023) >> 6;
        const int d = n0 & 63;
        short* base = (rsel == 0) ? OQ : (rsel == 1 ? OK : OV);
        *(bf16x8*)&base[((size_t)(h * L_SEQ + L0 + row)) * HD + d] = val;
    }
#undef PHASE
#undef LDA
#undef STG_A
#undef STG_B
}

// ---------------------------------------------------------------------------
// K5: out-projection GEMM — 2-phase double-buffered staging (R9, passed)
// ---------------------------------------------------------------------------
__global__ __launch_bounds__(256)
void mfma_gemm_out(const short* __restrict__ A, const short* __restrict__ BT,
                   const float* __restrict__ bias, float* __restrict__ OF,
                   int N, int K)
{
    __shared__ __align__(16) short smem[24576];
    const int tid  = threadIdx.x;
    const int lane = tid & 63;
    const int wave = tid >> 6;
    const int wm = (wave >> 1) * 32;
    const int wn = (wave & 1) * 64;
    const int fid = blockIdx.y * 8 + blockIdx.x;
    const int nf  = (fid & 7) * 64 + (fid >> 3);
    const int bx  = nf & 7;
    const int by  = nf >> 3;
    const int frow = lane & 15;
    const int quad = lane >> 4;
    const int q8   = quad << 3;
    const int sx   = (frow & 14) << 2;

    const short* Ab = A  + (size_t)(by * 64) * K;
    const short* Bb = BT + (size_t)(bx * 128) * K;

#define OSTG(BASE, KOFF) do {                                               \
        _Pragma("unroll")                                                   \
        for (int q_ = 0; q_ < 2; ++q_) {                                    \
            const int idx_ = q_ * 256 + tid;                                \
            const int row_ = idx_ >> 3;                                     \
            const int c8_  = (idx_ & 7) << 3;                               \
            gload_lds16(Ab + (size_t)row_ * K + (KOFF) + (c8_ ^ ((row_ & 14) << 2)), \
                        &smem[(BASE) + (idx_ << 3)]);                       \
        }                                                                   \
        _Pragma("unroll")                                                   \
        for (int q_ = 0; q_ < 4; ++q_) {                                    \
            const int idx_ = q_ * 256 + tid;                                \
            const int row_ = idx_ >> 3;                                     \
            const int c8_  = (idx_ & 7) << 3;                               \
            gload_lds16(Bb + (size_t)row_ * K + (KOFF) + (c8_ ^ ((row_ & 14) << 2)), \
                        &smem[(BASE) + 4096 + (idx_ << 3)]);                \
        }                                                                   \
    } while (0)

#define OCOMP(BASE) do {                                                    \
        bf16x8 af_[2][2], bfv_[4][2];                                       \
        _Pragma("unroll")                                                   \
        for (int mi_ = 0; mi_ < 2; ++mi_)                                   \
            _Pragma("unroll")                                               \
            for (int ks_ = 0; ks_ < 2; ++ks_)                               \
                af_[mi_][ks_] = *(const bf16x8*)                            \
                    &smem[(BASE) + (wm + mi_ * 16 + frow) * 64 + ((ks_ * 32 + q8) ^ sx)]; \
        _Pragma("unroll")                                                   \
        for (int ni_ = 0; ni_ < 4; ++ni_)                                   \
            _Pragma("unroll")                                               \
            for (int ks_ = 0; ks_ < 2; ++ks_)                               \
                bfv_[ni_][ks_] = *(const bf16x8*)                           \
                    &smem[(BASE) + 4096 + (wn + ni_ * 16 + frow) * 64 + ((ks_ * 32 + q8) ^ sx)]; \
        _Pragma("unroll")                                                   \
        for (int mi_ = 0; mi_ < 2; ++mi_)                                   \
            _Pragma("unroll")                                               \
            for (int ni_ = 0; ni_ < 4; ++ni_) {                             \
                acc[mi_][ni_] = MFMA16(af_[mi_][0], bfv_[ni_][0], acc[mi_][ni_], 0, 0, 0); \
                acc[mi_][ni_] = MFMA16(af_[mi_][1], bfv_[ni_][1], acc[mi_][ni_], 0, 0, 0); \
            }                                                               \
        __builtin_amdgcn_sched_barrier(0);                                  \
        asm volatile("s_waitcnt vmcnt(0)" ::: "memory");                    \
        __builtin_amdgcn_s_barrier();                                       \
        __builtin_amdgcn_sched_barrier(0);                                  \
    } while (0)

    floatx4 acc[2][4] = {};

    OSTG(0, 0);
    asm volatile("s_waitcnt vmcnt(0)" ::: "memory");
    __builtin_amdgcn_s_barrier();
    __builtin_amdgcn_sched_barrier(0);

#pragma unroll 1
    for (int it = 0; it < 8; ++it) {
        const int k1 = (2 * it + 1) * 64;              // odd tile
        const int kn = ((2 * it + 2) & 15) * 64;       // next even (wrapped)
        OSTG(12288, k1);        // stage odd tile into buf1
        OCOMP(0);               // compute even tile from buf0
        OSTG(0, kn);            // stage next even into buf0 (wrapped at it=7)
        OCOMP(12288);           // compute odd tile from buf1
    }

    const int rq = quad << 2;
#pragma unroll
    for (int ni = 0; ni < 4; ++ni) {
        const int n = bx * 128 + wn + ni * 16 + frow;
        const float bv = bias[n];
#pragma unroll
        for (int mi = 0; mi < 2; ++mi)
#pragma unroll
            for (int r = 0; r < 4; ++r) {
                const int m = by * 64 + wm + mi * 16 + rq + r;
                OF[(size_t)m * N + n] = acc[mi][ni][r] + bv;
            }
    }
#undef OSTG
#undef OCOMP
}

// ---------------------------------------------------------------------------
// K2: per-(head,chunk) state sums — R10: XOR-swizzled transpose staging.
// The old write Vt[(c8+j)*SP + l] was a 16-way bank conflict: lanes sharing l
// differ only by c8 (8 rows x 36 dwords = 288 = 0 mod 32 -> same bank).
// Fix: col' = l ^ ((c8+j)&56) = l ^ c8 (j<8) spreads the 8 c8-lanes across
// 8 column chunks (~2 lanes/bank = free). Reads apply the same involution:
// chunk at col C read from C ^ (row&56). Pure layout change.
// ---------------------------------------------------------------------------
#define SP 72

__global__ __launch_bounds__(256, 4)
void chunk_state(const short* __restrict__ Kb, const short* __restrict__ Vb,
                 short* __restrict__ ScTb, float* __restrict__ zc)
{
    __shared__ __align__(16) short Vt[64 * SP];   // V^T: rows e, cols l (swz)
    __shared__ __align__(16) short Kt[64 * SP];   // K'^T: rows d, cols l (swz)
    const int c = blockIdx.x, h = blockIdx.y;
    const int tid = threadIdx.x, lane = tid & 63, wave = tid >> 6;
    const int frow = lane & 15;
    const int quad = lane >> 4;
    const int fko  = quad << 3;
    const int wm   = wave << 4;
    const short* Kg = Kb + ((size_t)h * L_SEQ + (size_t)c * CHUNK) * HD;
    const short* Vg = Vb + ((size_t)h * L_SEQ + (size_t)c * CHUNK) * HD;

#pragma unroll
    for (int q = 0; q < 2; ++q) {
        const int idx = q * 256 + tid;            // 512 chunks of 8
        const int l = idx >> 3, c8 = (idx & 7) << 3;
        const int lx = l ^ c8;                    // swizzled col (row&56 == c8)
        const bf16x8 vv = *(const bf16x8*)&Vg[l * 64 + c8];
        const bf16x8 kk = *(const bf16x8*)&Kg[l * 64 + c8];
#pragma unroll
        for (int j = 0; j < 8; ++j) {
            Vt[(c8 + j) * SP + lx] = vv[j];
            Kt[(c8 + j) * SP + lx] = kk[j];
        }
    }
    __syncthreads();

    const int arow = wm + frow;
    const int asw  = arow & 56;
    const bf16x8 af0 = *(const bf16x8*)&Vt[arow * SP + (fko ^ asw)];
    const bf16x8 af1 = *(const bf16x8*)&Vt[arow * SP + ((32 + fko) ^ asw)];

    floatx4 acc[4] = {};
#pragma unroll
    for (int n = 0; n < 4; ++n) {
        const int krow = n * 16 + frow;
        const int ksw  = krow & 56;
        const bf16x8 kf0 = *(const bf16x8*)&Kt[krow * SP + (fko ^ ksw)];
        const bf16x8 kf1 = *(const bf16x8*)&Kt[krow * SP + ((32 + fko) ^ ksw)];
        acc[n] = MFMA16(af0, kf0, acc[n], 0, 0, 0);
        acc[n] = MFMA16(af1, kf1, acc[n], 0, 0, 0);
    }

    short* Sout = ScTb + (size_t)(h * NCHUNK + c) * 4096;
#pragma unroll
    for (int n = 0; n < 4; ++n)
#pragma unroll
        for (int r = 0; r < 4; ++r) {
            const int e = wm + quad * 4 + r;
            const int d = n * 16 + frow;
            Sout[e * 64 + d] = f2bf(acc[n][r]);
        }

    if (wave == 0) {   // z[d] = sum_l K'[l][d] via all-ones A fragment
        bf16x8 ones;
#pragma unroll
        for (int j = 0; j < 8; ++j) ones[j] = (short)0x3F80;
        floatx4 zacc[4] = {};
#pragma unroll
        for (int n = 0; n < 4; ++n) {
            const int krow = n * 16 + frow;
            const int ksw  = krow & 56;
            const bf16x8 kf0 = *(const bf16x8*)&Kt[krow * SP + (fko ^ ksw)];
            const bf16x8 kf1 = *(const bf16x8*)&Kt[krow * SP + ((32 + fko) ^ ksw)];
            zacc[n] = MFMA16(ones, kf0, zacc[n], 0, 0, 0);
            zacc[n] = MFMA16(ones, kf1, zacc[n], 0, 0, 0);
        }
        if (quad == 0) {
#pragma unroll
            for (int n = 0; n < 4; ++n)
                zc[(size_t)(h * NCHUNK + c) * 64 + n * 16 + frow] = zacc[n][0];
        }
    }
}

// ---------------------------------------------------------------------------
// K3: exclusive prefix over chunks, 16-deep batches. (R7, passed)
// ---------------------------------------------------------------------------
__global__ __launch_bounds__(256)
void prefix_scan(const short* __restrict__ ScTb, const float* __restrict__ zc,
                 short* __restrict__ S0b)
{
    const int g = blockIdx.x * 256 + threadIdx.x;
    const int h  = g >> 12;
    const int ed = g & 4095;
    const int e  = ed >> 6;
    const int d  = ed & 63;
    const short* src = ScTb + (size_t)h * NCHUNK * 4096 + ed;
    float run = 0.f;
    for (int cb = 0; cb < NCHUNK; cb += 16) {
        short v[16];
#pragma unroll
        for (int u = 0; u < 16; ++u) v[u] = src[(size_t)(cb + u) * 4096];
#pragma unroll
        for (int u = 0; u < 16; ++u) {
            S0b[((size_t)((h * NCHUNK + cb + u) * 65 + e)) * 64 + d] = f2bf(run);
            run += bf2f(v[u]);
        }
    }
    if (g < NH * HD) {
        const int h2 = g >> 6, d2 = g & 63;
        float rz = 0.f;
        for (int cb = 0; cb < NCHUNK; cb += 16) {
            float w[16];
#pragma unroll
            for (int u = 0; u < 16; ++u)
                w[u] = zc[((size_t)(h2 * NCHUNK + cb + u)) * HD + d2];
#pragma unroll
            for (int u = 0; u < 16; ++u) {
                S0b[((size_t)((h2 * NCHUNK + cb + u) * 65 + 64)) * 64 + d2] = f2bf(rz);
                rz += w[u];
            }
        }
    }
}

// ---------------------------------------------------------------------------
// K4: per-(head,chunk) intra-chunk attention — R10: Vs transpose staging gets
// the same row-XOR swizzle as chunk_state (was 16-way write conflict).
// Row 64 (ones): 64&56 == 0 -> unswizzled, consistent both sides.
// Ks/Qs (row-major b128 writes) and As unchanged.
// ---------------------------------------------------------------------------
__global__ __launch_bounds__(256)
void chunk_attn(const short* __restrict__ Qb, const short* __restrict__ Kb,
                const short* __restrict__ Vb, const short* __restrict__ S0b,
                short* __restrict__ attn)
{
    __shared__ __align__(16) short Vs[65 * SP];   // V^T (swz), row 64 = ones
    __shared__ __align__(16) short Ks[64 * SP];   // K rows (l x d)
    __shared__ __align__(16) short Qs[64 * SP];   // Q rows (l x d)
    __shared__ __align__(16) short As[64 * SP];
    const int c = blockIdx.x, h = blockIdx.y;
    const int tid = threadIdx.x, lane = tid & 63, wave = tid >> 6;
    const size_t rb = ((size_t)h * L_SEQ + (size_t)c * CHUNK) * HD;
    const short* Qg = Qb + rb;
    const short* Kg = Kb + rb;
    const short* Vg = Vb + rb;
    const short* Sg = S0b + (size_t)(h * NCHUNK + c) * 65 * 64;

#pragma unroll
    for (int q = 0; q < 2; ++q) {
        const int idx = q * 256 + tid;
        const int row = idx >> 3, c8 = (idx & 7) << 3;
        const int rx  = row ^ c8;                 // swizzled col for V^T write
        const bf16x8 vv = *(const bf16x8*)&Vg[row * 64 + c8];
        const bf16x8 kk = *(const bf16x8*)&Kg[row * 64 + c8];
        const bf16x8 qq = *(const bf16x8*)&Qg[row * 64 + c8];
#pragma unroll
        for (int j = 0; j < 8; ++j) Vs[(c8 + j) * SP + rx] = vv[j];    // V^T
        *(bf16x8*)&Ks[row * SP + c8] = kk;                             // K rows
        *(bf16x8*)&Qs[row * SP + c8] = qq;                             // Q rows
    }
    if (tid < 64) Vs[64 * SP + tid] = (short)0x3F80;   // ones (row64&56==0)
    __syncthreads();

    const int frow = lane & 15;
    const int quad = lane >> 4;
    const int fko  = quad << 3;
    const int wm   = wave << 4;

    const bf16x8 qf0 = *(const bf16x8*)&Qs[(wm + frow) * SP + fko];
    const bf16x8 qf1 = *(const bf16x8*)&Qs[(wm + frow) * SP + 32 + fko];

    floatx4 sacc[4] = {};
#pragma unroll
    for (int n = 0; n < 4; ++n) {
        const bf16x8 kf0 = *(const bf16x8*)&Ks[(n * 16 + frow) * SP + fko];
        const bf16x8 kf1 = *(const bf16x8*)&Ks[(n * 16 + frow) * SP + 32 + fko];
        sacc[n] = MFMA16(qf0, kf0, sacc[n], 0, 0, 0);
        sacc[n] = MFMA16(qf1, kf1, sacc[n], 0, 0, 0);
    }
#pragma unroll
    for (int n = 0; n < 4; ++n)
#pragma unroll
        for (int r = 0; r < 4; ++r) {
            const int i = wm + quad * 4 + r;
            const int j = n * 16 + frow;
            As[i * SP + j] = (j <= i) ? f2bf(sacc[n][r]) : (short)0;
        }
    const bf16x8 af0 = *(const bf16x8*)&As[(wm + frow) * SP + fko];
    const bf16x8 af1 = *(const bf16x8*)&As[(wm + frow) * SP + 32 + fko];

    floatx4 oacc[5] = {};
#pragma unroll
    for (int n = 0; n < 4; ++n) {
        const int vrow = n * 16 + frow;
        const int vsw  = vrow & 56;
        const bf16x8 vf0 = *(const bf16x8*)&Vs[vrow * SP + (fko ^ vsw)];
        const bf16x8 vf1 = *(const bf16x8*)&Vs[vrow * SP + ((32 + fko) ^ vsw)];
        oacc[n] = MFMA16(af0, vf0, oacc[n], 0, 0, 0);
        oacc[n] = MFMA16(af1, vf1, oacc[n], 0, 0, 0);
        const bf16x8 sf0 = *(const bf16x8*)&Sg[(n * 16 + frow) * 64 + fko];
        const bf16x8 sf1 = *(const bf16x8*)&Sg[(n * 16 + frow) * 64 + 32 + fko];
        oacc[n] = MFMA16(qf0, sf0, oacc[n], 0, 0, 0);
        oacc[n] = MFMA16(qf1, sf1, oacc[n], 0, 0, 0);
    }
    {   // tile 4: broadcast row 64 (ones / z0) -> col 64 = norm
        const bf16x8 vf0 = *(const bf16x8*)&Vs[64 * SP + fko];
        const bf16x8 vf1 = *(const bf16x8*)&Vs[64 * SP + 32 + fko];
        oacc[4] = MFMA16(af0, vf0, oacc[4], 0, 0, 0);
        oacc[4] = MFMA16(af1, vf1, oacc[4], 0, 0, 0);
        const bf16x8 sf0 = *(const bf16x8*)&Sg[64 * 64 + fko];
        const bf16x8 sf1 = *(const bf16x8*)&Sg[64 * 64 + 32 + fko];
        oacc[4] = MFMA16(qf0, sf0, oacc[4], 0, 0, 0);
        oacc[4] = MFMA16(qf1, sf1, oacc[4], 0, 0, 0);
    }
#pragma unroll
    for (int r = 0; r < 4; ++r) {
        const float norm = __shfl(oacc[4][r], lane & 48) + EPS;
        const float inv = 1.f / norm;
        const int i = wm + quad * 4 + r;
#pragma unroll
        for (int n = 0; n < 4; ++n)
            As[i * SP + n * 16 + frow] = f2bf(oacc[n][r] * inv);
    }
    __syncthreads();
#pragma unroll
    for (int t = 0; t < 2; ++t) {
        const int idx = t * 256 + tid;
        const int row = idx >> 3, c8 = (idx & 7) << 3;
        *(bf16x8*)&attn[(size_t)(c * CHUNK + row) * EMB + h * HD + c8] =
            *(const bf16x8*)&As[row * SP + c8];
    }
}

// ---------------------------------------------------------------------------
extern "C" void kernel_launch(void* const* d_in, const int* in_sizes, int n_in,
                              void* d_out, int out_size, void* d_ws, size_t ws_size,
                              hipStream_t stream)
{
    const float* x     = (const float*)d_in[0];
    const float* qkv_w = (const float*)d_in[1];
    const float* qkv_b = (const float*)d_in[2];
    const float* out_w = (const float*)d_in[3];
    const float* out_b = (const float*)d_in[4];
    float* out = (float*)d_out;

    short* ws    = (short*)d_ws;
    short* Qb    = ws;                   // head-major bf16, 4194304 each
    short* Kb    = Qb + 4194304;
    short* Vb    = Kb + 4194304;
    short* xb    = Vb + 4194304;
    short* qwt   = xb + 4194304;         // 3072 x 1024
    short* owt   = qwt + 3145728;        // 1024 x 1024
    short* attnb = owt + 1048576;        // 4096 x 1024
    short* ScTb  = attnb + 4194304;      // 1024 * 64 * 64
    short* S0b   = ScTb + 4194304;       // 1024 * 65 * 64
    float* zc    = (float*)(S0b + 4259840);    // 65536 fp32

    prep<<<dim3(3072), 256, 0, stream>>>(x, xb, qkv_w, qwt, out_w, owt);
    mfma_gemm_qkv256<<<dim3(16, 32), 256, 0, stream>>>(
        xb, qwt, qkv_b, Qb, Kb, Vb);
    chunk_state<<<dim3(NCHUNK, NH), 256, 0, stream>>>(Kb, Vb, ScTb, zc);
    prefix_scan<<<dim3((NH * 4096) / 256), 256, 0, stream>>>(ScTb, zc, S0b);
    chunk_attn<<<dim3(NCHUNK, NH), 256, 0, stream>>>(Qb, Kb, Vb, S0b, attnb);
    mfma_gemm_out<<<dim3(EMB / 128, L_SEQ / 64), 256, 0, stream>>>(
        attnb, owt, out_b, out, EMB, EMB);
}